// Round 1
// 630.712 us; speedup vs baseline: 1.0996x; 1.0996x over previous
//
#include <hip/hip_runtime.h>
#include <math.h>

#define HH    512
#define NHEAD 8
#define DHEAD 64
#define BB    4096
#define NNB   8192
#define SS    16
#define KNB   16
#define GG    (BB + NNB)   // 12288

typedef unsigned short ushort_t;
typedef __attribute__((ext_vector_type(8))) short short8;
typedef __attribute__((ext_vector_type(4))) float float4v;

// RNE float -> bf16 bits (inputs finite)
__device__ __forceinline__ ushort_t f2bf(float f) {
    unsigned int u = __float_as_uint(f);
    unsigned int r = (u + 0x7fffu + ((u >> 16) & 1u)) >> 16;
    return (ushort_t)r;
}
__device__ __forceinline__ float bf2f(ushort_t u) {
    return __uint_as_float(((unsigned int)u) << 16);
}

// async global->LDS, 16B per lane, dest = wave-uniform base + lane*16
#define GLD16(gp, lp) __builtin_amdgcn_global_load_lds( \
    (const __attribute__((address_space(1))) unsigned int*)(gp), \
    (__attribute__((address_space(3))) unsigned int*)(lp), 16, 0, 0)

// ---------------------------------------------------------------------------
// Kernel 1: masked mean over S -> bf16. One block per row.
// ---------------------------------------------------------------------------
__global__ __launch_bounds__(256) void mean_kernel(
    const float* __restrict__ span_out, const float* __restrict__ nb_out,
    const int* __restrict__ span_mask, const int* __restrict__ nb_mask,
    ushort_t* __restrict__ mean)
{
    int row = blockIdx.x;
    const float* src; const int* msk;
    if (row < BB) { src = span_out + (size_t)row * SS * HH; msk = span_mask + (size_t)row * SS; }
    else          { int r = row - BB; src = nb_out + (size_t)r * SS * HH; msk = nb_mask + (size_t)r * SS; }

    __shared__ float keep[SS];
    if (threadIdx.x < SS) keep[threadIdx.x] = (msk[threadIdx.x] != 1) ? 1.0f : 0.0f;
    __syncthreads();

    float cnt = 0.0f;
#pragma unroll
    for (int s = 0; s < SS; s++) cnt += keep[s];
    float inv = 1.0f / cnt;

    const float2* s2 = (const float2*)src;
    int t = threadIdx.x;
    float ax = 0.0f, ay = 0.0f;
#pragma unroll
    for (int s = 0; s < SS; s++) {
        float2 v = s2[s * (HH / 2) + t];
        float k = keep[s];
        ax += k * v.x;
        ay += k * v.y;
    }
    // lrelu applied downstream? no: mean feeds GEMM directly (reference applies
    // lrelu AFTER proj GEMM's input mean... actually lrelu is on mean result) —
    // NOTE: reference does lrelu(masked_mean) ONLY for b_hidden/n_hidden which
    // is all_h = lrelu(mean @ projW + b)?  No: b_hidden = lrelu(mean(p)) where
    // p = span_output @ projW + b.  We compute mean first then GEMM: identical
    // because mean and matmul commute; lrelu is applied in the GEMM epilogue.
    unsigned int o = (unsigned int)f2bf(ax * inv) | ((unsigned int)f2bf(ay * inv) << 16);
    ((unsigned int*)mean)[(size_t)row * (HH / 2) + t] = o;
}

// ---------------------------------------------------------------------------
// Kernel 2: repack ws_W (HOP,HEAD,H,D) -> WcatT bf16 [hop][n=e*64+d][k]
// ---------------------------------------------------------------------------
__global__ __launch_bounds__(256) void repack_ws_kernel(
    const float* __restrict__ wsW, ushort_t* __restrict__ WcatT)
{
    int idx = blockIdx.x * 256 + threadIdx.x;        // < 2*512*512
    int hop = idx >> 18;
    int rem = idx & 262143;
    int n = rem >> 9;          // e*64+d
    int k = rem & 511;
    int e = n >> 6, d = n & 63;
    WcatT[idx] = f2bf(wsW[(((size_t)hop * NHEAD + e) * HH + k) * DHEAD + d]);
}

// ---------------------------------------------------------------------------
// Kernel 2b: tiled transpose+convert: out_bf[n*K+k] = bf16(in[k*N+n])
// ---------------------------------------------------------------------------
__global__ __launch_bounds__(256) void tconv_kernel(
    const float* __restrict__ in, ushort_t* __restrict__ out, int K, int N)
{
    __shared__ float t[32][33];
    int kb = blockIdx.x % (K / 32);
    int nb = blockIdx.x / (K / 32);
    int x = threadIdx.x & 31, y = threadIdx.x >> 5;   // y in 0..7
#pragma unroll
    for (int i = 0; i < 4; i++)
        t[y + 8 * i][x] = in[(size_t)(kb * 32 + y + 8 * i) * N + nb * 32 + x];
    __syncthreads();
#pragma unroll
    for (int i = 0; i < 4; i++)
        out[(size_t)(nb * 32 + y + 8 * i) * K + kb * 32 + x] = f2bf(t[x][y + 8 * i]);
}

// ---------------------------------------------------------------------------
// Kernel 2c: repack gat_W [hop][e][c=128][d=64] fp32 -> WgT [hop][e][d][c] bf16
// ---------------------------------------------------------------------------
__global__ __launch_bounds__(256) void repack_gat_kernel(
    const float* __restrict__ gatW, ushort_t* __restrict__ WgT)
{
    int idx = blockIdx.x * 256 + threadIdx.x;   // < 2*8*64*128 = 131072
    int he = idx >> 13;            // hop*8+e
    int d  = (idx >> 7) & 63;
    int c  = idx & 127;
    WgT[idx] = f2bf(gatW[((size_t)he * 128 + c) * 64 + d]);
}

// ---------------------------------------------------------------------------
// Kernel 3: empty flags
// ---------------------------------------------------------------------------
__global__ __launch_bounds__(256) void empty_kernel(
    const int* __restrict__ gmap, int* __restrict__ empty)
{
    int n = blockIdx.x * 256 + threadIdx.x;
    if (n >= GG) return;
    int all_neg = 1;
#pragma unroll
    for (int k = 0; k < KNB; k++) all_neg &= (gmap[(size_t)n * KNB + k] == -1) ? 1 : 0;
    empty[n] = all_neg;
}

// ---------------------------------------------------------------------------
// Kernel 4: MFMA GEMM  Out = lrelu(A @ W + bias), A bf16 MxK row-major,
// Wt bf16 [N][K]. BM=BN=128, BK=32; 4 waves, 64x64 each, fp32 acc.
// Both operands staged via global_load_lds width=16 (m97 pattern).
// ---------------------------------------------------------------------------
#define BM 128
#define BN 128
#define BK 32
template<bool OUTF>
__global__ __launch_bounds__(256) void gemm_bf16(
    const ushort_t* __restrict__ A, const ushort_t* __restrict__ Wt,
    const float* __restrict__ bias, ushort_t* __restrict__ OutB,
    float* __restrict__ OutF, int M, int N, int K)
{
    __shared__ __align__(16) ushort_t As[BM * BK];   // linear [m][k], 8KB
    __shared__ __align__(16) ushort_t Bs[BN * BK];   // linear [n][k], 8KB
    int nb = N / BN;
    int by = blockIdx.x / nb, bx = blockIdx.x % nb;
    int row0 = by * BM, col0 = bx * BN;
    int tid = threadIdx.x;
    int lane = tid & 63, w = tid >> 6;
    int wr = (w >> 1) * 64, wc = (w & 1) * 64;
    int l15 = lane & 15, quad = lane >> 4;

    // staging geometry: chunk = 1KB = 16 rows of 32 bf16; wave w owns chunks
    // 2w and 2w+1 of both As and Bs. lane l -> row +l/4, k-elem (l%4)*8.
    int lm = lane >> 2;
    int lk = (lane & 3) * 8;
    const ushort_t* ag0 = A  + (size_t)(row0 + (2 * w + 0) * 16 + lm) * K + lk;
    const ushort_t* ag1 = A  + (size_t)(row0 + (2 * w + 1) * 16 + lm) * K + lk;
    const ushort_t* bg0 = Wt + (size_t)(col0 + (2 * w + 0) * 16 + lm) * K + lk;
    const ushort_t* bg1 = Wt + (size_t)(col0 + (2 * w + 1) * 16 + lm) * K + lk;
    ushort_t* al0 = &As[(2 * w + 0) * 512];
    ushort_t* al1 = &As[(2 * w + 1) * 512];
    ushort_t* bl0 = &Bs[(2 * w + 0) * 512];
    ushort_t* bl1 = &Bs[(2 * w + 1) * 512];

    float4v acc[4][4] = {};

    for (int k0 = 0; k0 < K; k0 += BK) {
        GLD16(ag0, al0);
        GLD16(ag1, al1);
        GLD16(bg0, bl0);
        GLD16(bg1, bl1);
        ag0 += BK; ag1 += BK; bg0 += BK; bg1 += BK;
        __syncthreads();   // compiler drains vmcnt(0) before s_barrier

        short8 af[4], bfr[4];
#pragma unroll
        for (int i = 0; i < 4; i++)
            af[i] = *(const short8*)&As[(wr + i * 16 + l15) * BK + quad * 8];
#pragma unroll
        for (int j = 0; j < 4; j++)
            bfr[j] = *(const short8*)&Bs[(wc + j * 16 + l15) * BK + quad * 8];
#pragma unroll
        for (int i = 0; i < 4; i++)
#pragma unroll
            for (int j = 0; j < 4; j++)
                acc[i][j] = __builtin_amdgcn_mfma_f32_16x16x32_bf16(
                    af[i], bfr[j], acc[i][j], 0, 0, 0);
        __syncthreads();
    }

#pragma unroll
    for (int i = 0; i < 4; i++) {
#pragma unroll
        for (int r = 0; r < 4; r++) {
            int rr = row0 + wr + i * 16 + quad * 4 + r;
#pragma unroll
            for (int j = 0; j < 4; j++) {
                int cc = col0 + wc + j * 16 + l15;
                float v = acc[i][j][r] + bias[cc];
                v = (v < 0.0f) ? 0.01f * v : v;
                if (OUTF) OutF[(size_t)rr * N + cc] = v;
                else      OutB[(size_t)rr * N + cc] = f2bf(v);
            }
        }
    }
}

// ---------------------------------------------------------------------------
// Kernel 5a: attention mixing over bf16 ch. One wave per (n,e); lane =
// (k = lane>>2, j = lane&3). Scores via shuffles, Sum_k attn*ctx via
// per-wave LDS transpose. Writes comb = [mixed | node] bf16 (G x 1024).
// ---------------------------------------------------------------------------
__global__ __launch_bounds__(256) void attn_mix_kernel(
    const ushort_t* __restrict__ ch, const int* __restrict__ gmap,
    ushort_t* __restrict__ comb, int n_out)
{
    __shared__ float sred[4][16 * 68];   // per-wave 16 rows, stride 68 (pad)
    int wid = threadIdx.x >> 6, lane = threadIdx.x & 63;
    int gid = blockIdx.x * 4 + wid;
    int n = gid >> 3, e = gid & 7;
    if (n >= n_out) return;
    int j = lane & 3, k = lane >> 2;

    int m = gmap[(size_t)n * KNB + k];
    int sm = (m < 0) ? 0 : m;

    const short8* ctxp = (const short8*)(ch + (size_t)sm * HH + e * DHEAD + j * 16);
    const short8* nodp = (const short8*)(ch + (size_t)n  * HH + e * DHEAD + j * 16);
    short8 cv0 = ctxp[0], cv1 = ctxp[1];
    short8 nv0 = nodp[0], nv1 = nodp[1];
    float c[16], nd[16];
#pragma unroll
    for (int i = 0; i < 8; i++) {
        c[i]      = bf2f((ushort_t)cv0[i]);
        c[8 + i]  = bf2f((ushort_t)cv1[i]);
        nd[i]     = bf2f((ushort_t)nv0[i]);
        nd[8 + i] = bf2f((ushort_t)nv1[i]);
    }

    float p = 0.0f;
#pragma unroll
    for (int i = 0; i < 16; i++) p += c[i] * nd[i];
    p += __shfl_xor(p, 1, 64);
    p += __shfl_xor(p, 2, 64);

    float sc = (m < 0) ? -1e9f : p;
    float mx = sc;
#pragma unroll
    for (int off = 4; off <= 32; off <<= 1) mx = fmaxf(mx, __shfl_xor(mx, off, 64));
    float ex = __expf(sc - mx);
    float ssum = ex;
#pragma unroll
    for (int off = 4; off <= 32; off <<= 1) ssum += __shfl_xor(ssum, off, 64);
    float at = ex / ssum;

    float* red = &sred[wid][k * 68 + j * 16];
#pragma unroll
    for (int q = 0; q < 4; q++) {
        float4v t;
#pragma unroll
        for (int i = 0; i < 4; i++) t[i] = c[q * 4 + i] * at;
        ((float4v*)red)[q] = t;
    }

    // lane d sums the 16 neighbor contributions for its output dim
    const float* base = &sred[wid][lane];
    float acc = 0.0f;
#pragma unroll
    for (int kk = 0; kk < KNB; kk++) acc += base[kk * 68];

    size_t cb = (size_t)n * (NHEAD * 128) + e * 128 + lane;
    comb[cb]      = f2bf(acc);
    comb[cb + 64] = ch[(size_t)n * HH + e * DHEAD + lane];   // already bf16
}

// ---------------------------------------------------------------------------
// Kernel 5b: per-head GAT GEMM: dst[r][e*64+d'] = (empty[r] ? 0 :
//   tanh( sum_c comb[r][e*128+c] * WgT[e][d'][c] + gatB[e][d'] ) )  -> bf16
// grid = (Mrows/128) * 8 heads; K=128 single stage.
// ---------------------------------------------------------------------------
#define GAK 136
__global__ __launch_bounds__(256) void gat_gemm_kernel(
    const ushort_t* __restrict__ comb, const ushort_t* __restrict__ WgT,
    const float* __restrict__ gatB, const int* __restrict__ empty,
    ushort_t* __restrict__ dst, int Mrows)
{
    __shared__ __align__(16) ushort_t As[128 * GAK];
    __shared__ __align__(16) ushort_t Bs[64 * GAK];
    int e = blockIdx.x & 7;
    int row0 = (blockIdx.x >> 3) * 128;
    int tid = threadIdx.x;

#pragma unroll
    for (int i = 0; i < 8; i++) {
        int f = tid + i * 256;            // 0..2047
        int r = f >> 4, c8 = f & 15;
        *(short8*)&As[r * GAK + c8 * 8] =
            *(const short8*)(comb + (size_t)(row0 + r) * 1024 + e * 128 + c8 * 8);
    }
#pragma unroll
    for (int i = 0; i < 4; i++) {
        int f = tid + i * 256;            // 0..1023
        int r = f >> 4, c8 = f & 15;
        *(short8*)&Bs[r * GAK + c8 * 8] =
            *(const short8*)(WgT + (size_t)e * 8192 + r * 128 + c8 * 8);
    }
    __syncthreads();

    int lane = tid & 63, w = tid >> 6;
    int l15 = lane & 15, quad = lane >> 4;
    int wr = w * 32;
    float4v acc[2][4] = {};
#pragma unroll
    for (int kq = 0; kq < 4; kq++) {
        short8 af[2], bfr[4];
#pragma unroll
        for (int mi = 0; mi < 2; mi++)
            af[mi] = *(const short8*)&As[(wr + mi * 16 + l15) * GAK + kq * 32 + quad * 8];
#pragma unroll
        for (int nj = 0; nj < 4; nj++)
            bfr[nj] = *(const short8*)&Bs[(nj * 16 + l15) * GAK + kq * 32 + quad * 8];
#pragma unroll
        for (int mi = 0; mi < 2; mi++)
#pragma unroll
            for (int nj = 0; nj < 4; nj++)
                acc[mi][nj] = __builtin_amdgcn_mfma_f32_16x16x32_bf16(
                    af[mi], bfr[nj], acc[mi][nj], 0, 0, 0);
    }

#pragma unroll
    for (int mi = 0; mi < 2; mi++) {
#pragma unroll
        for (int r = 0; r < 4; r++) {
            int rr = row0 + wr + mi * 16 + quad * 4 + r;
            int emp = empty[rr];
#pragma unroll
            for (int nj = 0; nj < 4; nj++) {
                int cc = nj * 16 + l15;
                float v = tanhf(acc[mi][nj][r] + gatB[e * 64 + cc]);
                dst[(size_t)rr * HH + e * 64 + cc] = emp ? (ushort_t)0 : f2bf(v);
            }
        }
    }
}

// ---------------------------------------------------------------------------
// Kernel 6: Af = [bf16(span_hidden) | (empty ? b_hidden : c1)]  (all bf16)
// ---------------------------------------------------------------------------
__global__ __launch_bounds__(256) void afinal_kernel(
    const float* __restrict__ span_hidden, const ushort_t* __restrict__ all_h,
    const ushort_t* __restrict__ c1, const int* __restrict__ empty,
    ushort_t* __restrict__ Af)
{
    int idx = blockIdx.x * 256 + threadIdx.x;
    int n = idx >> 10, col = idx & 1023;
    ushort_t v;
    if (col < HH) v = f2bf(span_hidden[(size_t)n * HH + col]);
    else {
        int cc = col - HH;
        v = empty[n] ? all_h[(size_t)n * HH + cc] : c1[(size_t)n * HH + cc];
    }
    Af[idx] = v;
}

// ---------------------------------------------------------------------------
extern "C" void kernel_launch(void* const* d_in, const int* in_sizes, int n_in,
                              void* d_out, int out_size, void* d_ws, size_t ws_size,
                              hipStream_t stream)
{
    const float* span_hidden = (const float*)d_in[0];
    const float* span_output = (const float*)d_in[1];
    const float* nb_output   = (const float*)d_in[2];
    const int*   span_mask   = (const int*)d_in[3];
    const int*   nb_mask     = (const int*)d_in[4];
    const int*   graph_map   = (const int*)d_in[5];
    const float* proj_W = (const float*)d_in[6];
    const float* proj_b = (const float*)d_in[7];
    const float* ws_W   = (const float*)d_in[8];
    const float* ws_b   = (const float*)d_in[9];
    const float* gat_W  = (const float*)d_in[10];
    const float* gat_b  = (const float*)d_in[11];
    const float* ff_W   = (const float*)d_in[12];
    const float* ff_b   = (const float*)d_in[13];
    float* out = (float*)d_out;

    char* w = (char*)d_ws;
    size_t off = 0;
    const size_t SZ_GH = (size_t)GG * HH * sizeof(ushort_t);   // 12.58 MB
    ushort_t* buf0  = (ushort_t*)(w + off); off += SZ_GH;   // mean -> chbuf -> Af
    ushort_t* all_h = (ushort_t*)(w + off); off += SZ_GH;
    ushort_t* buf2  = (ushort_t*)(w + off); off += SZ_GH;   // cbuf -> c1
    ushort_t* comb  = (ushort_t*)(w + off); off += (size_t)GG * 1024 * sizeof(ushort_t);
    ushort_t* WcatT = (ushort_t*)(w + off); off += (size_t)2 * HH * HH * sizeof(ushort_t);
    ushort_t* wslot = (ushort_t*)(w + off); off += (size_t)2 * HH * HH * sizeof(ushort_t);
    ushort_t* WgT   = (ushort_t*)(w + off); off += (size_t)2 * NHEAD * 64 * 128 * sizeof(ushort_t);
    int*      empty = (int*)(w + off);      off += (size_t)GG * sizeof(int);
    (void)ws_size; (void)in_sizes; (void)n_in; (void)out_size;

    ushort_t* mean  = buf0;
    ushort_t* chbuf = buf0;
    ushort_t* cbuf  = buf2;
    ushort_t* c1    = buf2;
    ushort_t* Af    = buf0;
    ushort_t* projT = wslot;
    ushort_t* ffT   = wslot;

    // 1. masked means (bf16 out)
    mean_kernel<<<GG, 256, 0, stream>>>(span_output, nb_output, span_mask, nb_mask, mean);
    // 2. weight prep + empty flags
    repack_ws_kernel<<<(2 * HH * HH) / 256, 256, 0, stream>>>(ws_W, WcatT);
    tconv_kernel<<<(HH / 32) * (HH / 32), 256, 0, stream>>>(proj_W, projT, HH, HH);
    repack_gat_kernel<<<(2 * NHEAD * 64 * 128) / 256, 256, 0, stream>>>(gat_W, WgT);
    empty_kernel<<<(GG + 255) / 256, 256, 0, stream>>>(graph_map, empty);
    // 3. all_h = lrelu(mean @ proj_W + proj_b)   (bf16 out)
    gemm_bf16<false><<<(GG / BM) * (HH / BN), 256, 0, stream>>>(
        mean, projT, proj_b, all_h, nullptr, GG, HH, HH);
    tconv_kernel<<<((2 * HH) / 32) * (HH / 32), 256, 0, stream>>>(ff_W, ffT, 2 * HH, HH);
    // 4. hop 0
    gemm_bf16<false><<<(GG / BM) * (HH / BN), 256, 0, stream>>>(
        all_h, WcatT, ws_b, chbuf, nullptr, GG, HH, HH);
    attn_mix_kernel<<<(GG * NHEAD) / 4, 256, 0, stream>>>(chbuf, graph_map, comb, GG);
    gat_gemm_kernel<<<(GG / 128) * 8, 256, 0, stream>>>(
        comb, WgT, gat_b, empty, cbuf, GG);
    // 5. hop 1
    gemm_bf16<false><<<(GG / BM) * (HH / BN), 256, 0, stream>>>(
        cbuf, WcatT + (size_t)HH * HH, ws_b + HH, chbuf, nullptr, GG, HH, HH);
    attn_mix_kernel<<<(BB * NHEAD) / 4, 256, 0, stream>>>(chbuf, graph_map, comb, BB);
    gat_gemm_kernel<<<(BB / 128) * 8, 256, 0, stream>>>(
        comb, WgT + (size_t)NHEAD * 64 * 128, gat_b + NHEAD * DHEAD, empty, c1, BB);
    // 6. Af = [span_hidden | where(empty, b_hidden, c1)]  (bf16)
    afinal_kernel<<<(BB * 2 * HH) / 256, 256, 0, stream>>>(
        span_hidden, all_h, c1, empty, Af);
    // 7. out = lrelu(Af @ ff_W + ff_b)  (fp32 out)
    gemm_bf16<true><<<(BB / BM) * (HH / BN), 256, 0, stream>>>(
        Af, ffT, ff_b, nullptr, out, BB, HH, 2 * HH);
}

// Round 3
// 601.674 us; speedup vs baseline: 1.1527x; 1.0483x over previous
//
#include <hip/hip_runtime.h>
#include <math.h>

#define HH    512
#define NHEAD 8
#define DHEAD 64
#define BB    4096
#define NNB   8192
#define SS    16
#define KNB   16
#define GG    (BB + NNB)   // 12288

typedef unsigned short ushort_t;
typedef __attribute__((ext_vector_type(8))) short short8;
typedef __attribute__((ext_vector_type(4))) float float4v;

// RNE float -> bf16 bits (inputs finite)
__device__ __forceinline__ ushort_t f2bf(float f) {
    unsigned int u = __float_as_uint(f);
    unsigned int r = (u + 0x7fffu + ((u >> 16) & 1u)) >> 16;
    return (ushort_t)r;
}
__device__ __forceinline__ float bf2f(ushort_t u) {
    return __uint_as_float(((unsigned int)u) << 16);
}

// async global->LDS, 16B per lane, dest = wave-uniform base + lane*16
#define GLD16(gp, lp) __builtin_amdgcn_global_load_lds( \
    (const __attribute__((address_space(1))) unsigned int*)(gp), \
    (__attribute__((address_space(3))) unsigned int*)(lp), 16, 0, 0)

// ---------------------------------------------------------------------------
// Kernel 1 (fused prep): block ranges do
//   [0,GG)          masked mean -> bf16
//   [GG,+2048)      repack ws_W
//   [+256)          tconv proj_W
//   [+512)          tconv ff_W
//   [+512)          repack gat_W
//   [+48)           empty flags
// ---------------------------------------------------------------------------
#define PB0 GG                 // 12288
#define PB1 (PB0 + 2048)       // repack_ws
#define PB2 (PB1 + 256)        // tconv proj (K=512)
#define PB3 (PB2 + 512)        // tconv ff   (K=1024)
#define PB4 (PB3 + 512)        // repack_gat
#define PB5 (PB4 + 48)         // empty

__device__ __forceinline__ void tconv_body(
    const float* __restrict__ in, ushort_t* __restrict__ out,
    int K, int N, int blk, float* sh)   // sh = [32][33]
{
    int kb = blk % (K / 32);
    int nb = blk / (K / 32);
    int x = threadIdx.x & 31, y = threadIdx.x >> 5;   // y in 0..7
#pragma unroll
    for (int i = 0; i < 4; i++)
        sh[(y + 8 * i) * 33 + x] = in[(size_t)(kb * 32 + y + 8 * i) * N + nb * 32 + x];
    __syncthreads();
#pragma unroll
    for (int i = 0; i < 4; i++)
        out[(size_t)(nb * 32 + y + 8 * i) * K + kb * 32 + x] = f2bf(sh[x * 33 + (y + 8 * i)]);
}

__global__ __launch_bounds__(256) void prep_kernel(
    const float* __restrict__ span_out, const float* __restrict__ nb_out,
    const int* __restrict__ span_mask, const int* __restrict__ nb_mask,
    ushort_t* __restrict__ mean,
    const float* __restrict__ wsW, ushort_t* __restrict__ WcatT,
    const float* __restrict__ projW, ushort_t* __restrict__ projT,
    const float* __restrict__ ffW, ushort_t* __restrict__ ffT,
    const float* __restrict__ gatW, ushort_t* __restrict__ WgT,
    const int* __restrict__ gmap, int* __restrict__ empty)
{
    __shared__ float sh[32 * 33];
    int b = blockIdx.x;
    if (b < PB0) {
        // ---- masked mean ----
        int row = b;
        const float* src; const int* msk;
        if (row < BB) { src = span_out + (size_t)row * SS * HH; msk = span_mask + (size_t)row * SS; }
        else          { int r = row - BB; src = nb_out + (size_t)r * SS * HH; msk = nb_mask + (size_t)r * SS; }
        float* keep = sh;
        if (threadIdx.x < SS) keep[threadIdx.x] = (msk[threadIdx.x] != 1) ? 1.0f : 0.0f;
        __syncthreads();
        float cnt = 0.0f;
#pragma unroll
        for (int s = 0; s < SS; s++) cnt += keep[s];
        float inv = 1.0f / cnt;
        const float2* s2 = (const float2*)src;
        int t = threadIdx.x;
        float ax = 0.0f, ay = 0.0f;
#pragma unroll
        for (int s = 0; s < SS; s++) {
            float2 v = s2[s * (HH / 2) + t];
            float k = keep[s];
            ax += k * v.x;
            ay += k * v.y;
        }
        unsigned int o = (unsigned int)f2bf(ax * inv) | ((unsigned int)f2bf(ay * inv) << 16);
        ((unsigned int*)mean)[(size_t)row * (HH / 2) + t] = o;
    } else if (b < PB1) {
        int idx = (b - PB0) * 256 + threadIdx.x;   // < 2*512*512
        int hop = idx >> 18;
        int rem = idx & 262143;
        int n = rem >> 9;          // e*64+d
        int k = rem & 511;
        int e = n >> 6, d = n & 63;
        WcatT[idx] = f2bf(wsW[(((size_t)hop * NHEAD + e) * HH + k) * DHEAD + d]);
    } else if (b < PB2) {
        tconv_body(projW, projT, HH, HH, b - PB1, sh);
    } else if (b < PB3) {
        tconv_body(ffW, ffT, 2 * HH, HH, b - PB2, sh);
    } else if (b < PB4) {
        int idx = (b - PB3) * 256 + threadIdx.x;   // < 131072
        int he = idx >> 13;            // hop*8+e
        int d  = (idx >> 7) & 63;
        int c  = idx & 127;
        WgT[idx] = f2bf(gatW[((size_t)he * 128 + c) * 64 + d]);
    } else {
        int n = (b - PB4) * 256 + threadIdx.x;
        if (n < GG) {
            int all_neg = 1;
#pragma unroll
            for (int k = 0; k < KNB; k++) all_neg &= (gmap[(size_t)n * KNB + k] == -1) ? 1 : 0;
            empty[n] = all_neg;
        }
    }
}

// ---------------------------------------------------------------------------
// Kernel 4: MFMA GEMM  Out = lrelu(A @ W + bias), bf16 A [M][K], Wt [N][K].
// BM=64, BN=128, BK=32; 4 waves (2x2, 32x64 each). Double-buffered LDS with
// the verified T3-minimum schedule: STAGE(next) || compute(cur), one
// vmcnt(0)+barrier per K-step.
// ---------------------------------------------------------------------------
#define BM 64
#define BN 128
#define BK 32
template<bool OUTF>
__global__ __launch_bounds__(256) void gemm_bf16(
    const ushort_t* __restrict__ A, const ushort_t* __restrict__ Wt,
    const float* __restrict__ bias, ushort_t* __restrict__ OutB,
    float* __restrict__ OutF, int M, int N, int K)
{
    __shared__ __align__(16) ushort_t As[2][BM * BK];   // 2 x 4KB
    __shared__ __align__(16) ushort_t Bs[2][BN * BK];   // 2 x 8KB
    int nb = N / BN;
    int by = blockIdx.x / nb, bx = blockIdx.x % nb;
    int row0 = by * BM, col0 = bx * BN;
    int tid = threadIdx.x;
    int lane = tid & 63, w = tid >> 6;
    int wr = (w >> 1) * 32, wc = (w & 1) * 64;
    int l15 = lane & 15, quad = lane >> 4;

    // staging: chunk = 16 rows x 32 bf16 = 1KB. A has 4 chunks (wave w -> w),
    // B has 8 chunks (wave w -> 2w, 2w+1). lane l -> row l/4, k (l%4)*8.
    int lm = lane >> 2;
    int lk = (lane & 3) * 8;
    const ushort_t* ag  = A  + (size_t)(row0 + w * 16 + lm) * K + lk;
    const ushort_t* bg0 = Wt + (size_t)(col0 + (2 * w + 0) * 16 + lm) * K + lk;
    const ushort_t* bg1 = Wt + (size_t)(col0 + (2 * w + 1) * 16 + lm) * K + lk;

    float4v acc[2][4] = {};
    int nt = K / BK;

    // prologue: stage tile 0 into buffer 0, drain, barrier
    GLD16(ag, &As[0][w * 512]);
    GLD16(bg0, &Bs[0][(2 * w) * 512]);
    GLD16(bg1, &Bs[0][(2 * w) * 512 + 512]);
    asm volatile("s_waitcnt vmcnt(0)" ::: "memory");
    __builtin_amdgcn_s_barrier();

    int cur = 0;
    for (int t = 0; t < nt; ++t) {
        if (t + 1 < nt) {
            int koff = (t + 1) * BK;
            GLD16(ag + koff, &As[cur ^ 1][w * 512]);
            GLD16(bg0 + koff, &Bs[cur ^ 1][(2 * w) * 512]);
            GLD16(bg1 + koff, &Bs[cur ^ 1][(2 * w) * 512 + 512]);
        }

        short8 af[2], bfr[4];
#pragma unroll
        for (int i = 0; i < 2; i++)
            af[i] = *(const short8*)&As[cur][(wr + i * 16 + l15) * BK + quad * 8];
#pragma unroll
        for (int j = 0; j < 4; j++)
            bfr[j] = *(const short8*)&Bs[cur][(wc + j * 16 + l15) * BK + quad * 8];
        asm volatile("s_waitcnt lgkmcnt(0)" ::: "memory");
        __builtin_amdgcn_sched_barrier(0);
        __builtin_amdgcn_s_setprio(1);
#pragma unroll
        for (int i = 0; i < 2; i++)
#pragma unroll
            for (int j = 0; j < 4; j++)
                acc[i][j] = __builtin_amdgcn_mfma_f32_16x16x32_bf16(
                    af[i], bfr[j], acc[i][j], 0, 0, 0);
        __builtin_amdgcn_s_setprio(0);

        if (t + 1 < nt) {
            asm volatile("s_waitcnt vmcnt(0)" ::: "memory");
        }
        __builtin_amdgcn_s_barrier();
        cur ^= 1;
    }

#pragma unroll
    for (int i = 0; i < 2; i++) {
#pragma unroll
        for (int r = 0; r < 4; r++) {
            int rr = row0 + wr + i * 16 + quad * 4 + r;
#pragma unroll
            for (int j = 0; j < 4; j++) {
                int cc = col0 + wc + j * 16 + l15;
                float v = acc[i][j][r] + bias[cc];
                v = (v < 0.0f) ? 0.01f * v : v;
                if (OUTF) OutF[(size_t)rr * N + cc] = v;
                else      OutB[(size_t)rr * N + cc] = f2bf(v);
            }
        }
    }
}

// ---------------------------------------------------------------------------
// Kernel 5a: attention mixing over bf16 ch (unchanged, verified round 1).
// ---------------------------------------------------------------------------
__global__ __launch_bounds__(256) void attn_mix_kernel(
    const ushort_t* __restrict__ ch, const int* __restrict__ gmap,
    ushort_t* __restrict__ comb, int n_out)
{
    __shared__ float sred[4][16 * 68];
    int wid = threadIdx.x >> 6, lane = threadIdx.x & 63;
    int gid = blockIdx.x * 4 + wid;
    int n = gid >> 3, e = gid & 7;
    if (n >= n_out) return;
    int j = lane & 3, k = lane >> 2;

    int m = gmap[(size_t)n * KNB + k];
    int sm = (m < 0) ? 0 : m;

    const short8* ctxp = (const short8*)(ch + (size_t)sm * HH + e * DHEAD + j * 16);
    const short8* nodp = (const short8*)(ch + (size_t)n  * HH + e * DHEAD + j * 16);
    short8 cv0 = ctxp[0], cv1 = ctxp[1];
    short8 nv0 = nodp[0], nv1 = nodp[1];
    float c[16], nd[16];
#pragma unroll
    for (int i = 0; i < 8; i++) {
        c[i]      = bf2f((ushort_t)cv0[i]);
        c[8 + i]  = bf2f((ushort_t)cv1[i]);
        nd[i]     = bf2f((ushort_t)nv0[i]);
        nd[8 + i] = bf2f((ushort_t)nv1[i]);
    }

    float p = 0.0f;
#pragma unroll
    for (int i = 0; i < 16; i++) p += c[i] * nd[i];
    p += __shfl_xor(p, 1, 64);
    p += __shfl_xor(p, 2, 64);

    float sc = (m < 0) ? -1e9f : p;
    float mx = sc;
#pragma unroll
    for (int off = 4; off <= 32; off <<= 1) mx = fmaxf(mx, __shfl_xor(mx, off, 64));
    float ex = __expf(sc - mx);
    float ssum = ex;
#pragma unroll
    for (int off = 4; off <= 32; off <<= 1) ssum += __shfl_xor(ssum, off, 64);
    float at = ex / ssum;

    float* red = &sred[wid][k * 68 + j * 16];
#pragma unroll
    for (int q = 0; q < 4; q++) {
        float4v t;
#pragma unroll
        for (int i = 0; i < 4; i++) t[i] = c[q * 4 + i] * at;
        ((float4v*)red)[q] = t;
    }

    const float* base = &sred[wid][lane];
    float acc = 0.0f;
#pragma unroll
    for (int kk = 0; kk < KNB; kk++) acc += base[kk * 68];

    size_t cb = (size_t)n * (NHEAD * 128) + e * 128 + lane;
    comb[cb]      = f2bf(acc);
    comb[cb + 64] = ch[(size_t)n * HH + e * DHEAD + lane];
}

// ---------------------------------------------------------------------------
// Kernel 5b: per-head GAT GEMM (unchanged, verified round 1).
// ---------------------------------------------------------------------------
#define GAK 136
__global__ __launch_bounds__(256) void gat_gemm_kernel(
    const ushort_t* __restrict__ comb, const ushort_t* __restrict__ WgT,
    const float* __restrict__ gatB, const int* __restrict__ empty,
    ushort_t* __restrict__ dst, int Mrows)
{
    __shared__ __align__(16) ushort_t As[128 * GAK];
    __shared__ __align__(16) ushort_t Bs[64 * GAK];
    int e = blockIdx.x & 7;
    int row0 = (blockIdx.x >> 3) * 128;
    int tid = threadIdx.x;

#pragma unroll
    for (int i = 0; i < 8; i++) {
        int f = tid + i * 256;
        int r = f >> 4, c8 = f & 15;
        *(short8*)&As[r * GAK + c8 * 8] =
            *(const short8*)(comb + (size_t)(row0 + r) * 1024 + e * 128 + c8 * 8);
    }
#pragma unroll
    for (int i = 0; i < 4; i++) {
        int f = tid + i * 256;
        int r = f >> 4, c8 = f & 15;
        *(short8*)&Bs[r * GAK + c8 * 8] =
            *(const short8*)(WgT + (size_t)e * 8192 + r * 128 + c8 * 8);
    }
    __syncthreads();

    int lane = tid & 63, w = tid >> 6;
    int l15 = lane & 15, quad = lane >> 4;
    int wr = w * 32;
    float4v acc[2][4] = {};
#pragma unroll
    for (int kq = 0; kq < 4; kq++) {
        short8 af[2], bfr[4];
#pragma unroll
        for (int mi = 0; mi < 2; mi++)
            af[mi] = *(const short8*)&As[(wr + mi * 16 + l15) * GAK + kq * 32 + quad * 8];
#pragma unroll
        for (int nj = 0; nj < 4; nj++)
            bfr[nj] = *(const short8*)&Bs[(nj * 16 + l15) * GAK + kq * 32 + quad * 8];
#pragma unroll
        for (int mi = 0; mi < 2; mi++)
#pragma unroll
            for (int nj = 0; nj < 4; nj++)
                acc[mi][nj] = __builtin_amdgcn_mfma_f32_16x16x32_bf16(
                    af[mi], bfr[nj], acc[mi][nj], 0, 0, 0);
    }

#pragma unroll
    for (int mi = 0; mi < 2; mi++) {
#pragma unroll
        for (int r = 0; r < 4; r++) {
            int rr = row0 + wr + mi * 16 + quad * 4 + r;
            int emp = empty[rr];
#pragma unroll
            for (int nj = 0; nj < 4; nj++) {
                int cc = nj * 16 + l15;
                float v = tanhf(acc[mi][nj][r] + gatB[e * 64 + cc]);
                dst[(size_t)rr * HH + e * 64 + cc] = emp ? (ushort_t)0 : f2bf(v);
            }
        }
    }
}

// ---------------------------------------------------------------------------
// Kernel 7: final GEMM with fused Af construction.
// A[r][c] = c<512 ? bf16(span_hidden[r][c]) : (empty[r] ? all_h : c1)[r][c-512]
// Out = lrelu(A @ ffT^T + ff_b), fp32. BM=64, BN=64, K=1024. 512 blocks.
// ---------------------------------------------------------------------------
__global__ __launch_bounds__(256) void final_gemm(
    const float* __restrict__ span_hidden, const ushort_t* __restrict__ all_h,
    const ushort_t* __restrict__ c1, const int* __restrict__ empty,
    const ushort_t* __restrict__ ffT, const float* __restrict__ ffb,
    float* __restrict__ Out)
{
    __shared__ __align__(16) ushort_t As[64 * 32];   // 4KB
    __shared__ __align__(16) ushort_t Bs[64 * 32];   // 4KB
    __shared__ int ef[64];
    int bx = blockIdx.x & 7;        // 8 col blocks
    int by = blockIdx.x >> 3;       // 64 row blocks
    int row0 = by * 64, col0 = bx * 64;
    int tid = threadIdx.x;
    int lane = tid & 63, w = tid >> 6;
    int l15 = lane & 15, quad = lane >> 4;
    int wr = (w >> 1) * 32, wc = (w & 1) * 32;

    if (tid < 64) ef[tid] = empty[row0 + tid];

    int lm = lane >> 2, lk = (lane & 3) * 8;
    const ushort_t* bg = ffT + (size_t)(col0 + w * 16 + lm) * 1024 + lk;
    ushort_t* bl = &Bs[w * 512];

    __syncthreads();   // ef visible

    float4v acc[2][2] = {};
    for (int t = 0; t < 32; ++t) {
        int k0 = t * 32;
        GLD16(bg, bl); bg += 32;
        if (k0 < 512) {
            // A from span_hidden fp32, coalesced: 2 passes x (8 rows x 8 float4)
#pragma unroll
            for (int p = 0; p < 2; ++p) {
                int f = tid + p * 256;
                int r = f >> 3, off = f & 7;
                float4v v = *(const float4v*)(span_hidden + (size_t)(row0 + r) * HH + k0 + off * 4);
                unsigned long long pk =
                    (unsigned long long)f2bf(v.x) | ((unsigned long long)f2bf(v.y) << 16) |
                    ((unsigned long long)f2bf(v.z) << 32) | ((unsigned long long)f2bf(v.w) << 48);
                *(unsigned long long*)&As[r * 32 + off * 4] = pk;
            }
        } else {
            // A from (empty ? all_h : c1), bf16: 1 pass x (16 rows x 4 short8)
            int r = tid >> 2, off = tid & 3;
            const ushort_t* src = (ef[r] ? all_h : c1) + (size_t)(row0 + r) * HH + (k0 - 512) + off * 8;
            *(short8*)&As[r * 32 + off * 8] = *(const short8*)src;
        }
        __syncthreads();

        short8 af[2], bfr[2];
#pragma unroll
        for (int i = 0; i < 2; i++)
            af[i] = *(const short8*)&As[(wr + i * 16 + l15) * 32 + quad * 8];
#pragma unroll
        for (int j = 0; j < 2; j++)
            bfr[j] = *(const short8*)&Bs[(wc + j * 16 + l15) * 32 + quad * 8];
#pragma unroll
        for (int i = 0; i < 2; i++)
#pragma unroll
            for (int j = 0; j < 2; j++)
                acc[i][j] = __builtin_amdgcn_mfma_f32_16x16x32_bf16(
                    af[i], bfr[j], acc[i][j], 0, 0, 0);
        __syncthreads();
    }

#pragma unroll
    for (int i = 0; i < 2; i++) {
#pragma unroll
        for (int r = 0; r < 4; r++) {
            int rr = row0 + wr + i * 16 + quad * 4 + r;
#pragma unroll
            for (int j = 0; j < 2; j++) {
                int cc = col0 + wc + j * 16 + l15;
                float v = acc[i][j][r] + ffb[cc];
                v = (v < 0.0f) ? 0.01f * v : v;
                Out[(size_t)rr * HH + cc] = v;
            }
        }
    }
}

// ---------------------------------------------------------------------------
extern "C" void kernel_launch(void* const* d_in, const int* in_sizes, int n_in,
                              void* d_out, int out_size, void* d_ws, size_t ws_size,
                              hipStream_t stream)
{
    const float* span_hidden = (const float*)d_in[0];
    const float* span_output = (const float*)d_in[1];
    const float* nb_output   = (const float*)d_in[2];
    const int*   span_mask   = (const int*)d_in[3];
    const int*   nb_mask     = (const int*)d_in[4];
    const int*   graph_map   = (const int*)d_in[5];
    const float* proj_W = (const float*)d_in[6];
    const float* proj_b = (const float*)d_in[7];
    const float* ws_W   = (const float*)d_in[8];
    const float* ws_b   = (const float*)d_in[9];
    const float* gat_W  = (const float*)d_in[10];
    const float* gat_b  = (const float*)d_in[11];
    const float* ff_W   = (const float*)d_in[12];
    const float* ff_b   = (const float*)d_in[13];
    float* out = (float*)d_out;

    char* w = (char*)d_ws;
    size_t off = 0;
    const size_t SZ_GH = (size_t)GG * HH * sizeof(ushort_t);   // 12.58 MB
    ushort_t* buf0  = (ushort_t*)(w + off); off += SZ_GH;   // mean -> chbuf
    ushort_t* all_h = (ushort_t*)(w + off); off += SZ_GH;
    ushort_t* buf2  = (ushort_t*)(w + off); off += SZ_GH;   // cbuf -> c1
    ushort_t* comb  = (ushort_t*)(w + off); off += (size_t)GG * 1024 * sizeof(ushort_t);
    ushort_t* WcatT = (ushort_t*)(w + off); off += (size_t)2 * HH * HH * sizeof(ushort_t);
    ushort_t* projT = (ushort_t*)(w + off); off += (size_t)HH * HH * sizeof(ushort_t);
    ushort_t* ffT   = (ushort_t*)(w + off); off += (size_t)HH * 2 * HH * sizeof(ushort_t);
    ushort_t* WgT   = (ushort_t*)(w + off); off += (size_t)2 * NHEAD * 64 * 128 * sizeof(ushort_t);
    int*      empty = (int*)(w + off);      off += (size_t)GG * sizeof(int);
    (void)ws_size; (void)in_sizes; (void)n_in; (void)out_size;

    ushort_t* mean  = buf0;
    ushort_t* chbuf = buf0;
    ushort_t* cbuf  = buf2;
    ushort_t* c1    = buf2;

    // 1. fused prep: mean + all weight repacks + empty flags
    prep_kernel<<<PB5, 256, 0, stream>>>(
        span_output, nb_output, span_mask, nb_mask, mean,
        ws_W, WcatT, proj_W, projT, ff_W, ffT, gat_W, WgT,
        graph_map, empty);
    // 2. all_h = lrelu(mean @ proj_W + proj_b)
    gemm_bf16<false><<<(GG / BM) * (HH / BN), 256, 0, stream>>>(
        mean, projT, proj_b, all_h, nullptr, GG, HH, HH);
    // 3. hop 0
    gemm_bf16<false><<<(GG / BM) * (HH / BN), 256, 0, stream>>>(
        all_h, WcatT, ws_b, chbuf, nullptr, GG, HH, HH);
    attn_mix_kernel<<<(GG * NHEAD) / 4, 256, 0, stream>>>(chbuf, graph_map, comb, GG);
    gat_gemm_kernel<<<(GG / 128) * 8, 256, 0, stream>>>(
        comb, WgT, gat_b, empty, cbuf, GG);
    // 4. hop 1
    gemm_bf16<false><<<(GG / BM) * (HH / BN), 256, 0, stream>>>(
        cbuf, WcatT + (size_t)HH * HH, ws_b + HH, chbuf, nullptr, GG, HH, HH);
    attn_mix_kernel<<<(BB * NHEAD) / 4, 256, 0, stream>>>(chbuf, graph_map, comb, BB);
    gat_gemm_kernel<<<(BB / 128) * 8, 256, 0, stream>>>(
        comb, WgT + (size_t)NHEAD * 64 * 128, gat_b + NHEAD * DHEAD, empty, c1, BB);
    // 5. out = lrelu([span_hidden | where(empty,b_hidden,c1)] @ ff_W + ff_b)
    final_gemm<<<(BB / 64) * (HH / 64), 256, 0, stream>>>(
        span_hidden, all_h, c1, empty, ffT, ff_b, out);
}